// Round 1
// baseline (532.482 us; speedup 1.0000x reference)
//
#include <hip/hip_runtime.h>
#include <hip/hip_bf16.h>

// Types
typedef __attribute__((ext_vector_type(8))) short bf16x8;
typedef __attribute__((ext_vector_type(16))) float f32x16;
typedef __attribute__((ext_vector_type(4))) unsigned short us4;
typedef __attribute__((ext_vector_type(8))) unsigned short us8;

#define BM 64   // rows per block

__device__ __forceinline__ unsigned short f2bf(float x) {
  unsigned u = __builtin_bit_cast(unsigned, x);
  u += 0x7fffu + ((u >> 16) & 1u);   // round-to-nearest-even
  return (unsigned short)(u >> 16);
}

// ---------------------------------------------------------------------------
// Pre-pass: fp32 weights -> bf16, laid out in exact MFMA B-fragment order.
// Fragment value for Wg/Wv (GEMM1 B):  W[h][k = ks*16 + (l>>5)*8 + j][n = c*64 + nc*32 + (l&31)]
//   frag index  t = (((h*8 + c)*2 + nc)*8 + ks)*64 + l          (131072 frags each)
// Fragment value for Wo (GEMM2 B):     Wo[h][f = c*64 + ks*16 + (l>>5)*8 + j][d = nc2*64 + nt*32 + (l&31)]
//   frag index  t = ((((h*8 + c)*2 + nc2)*2 + nt)*4 + ks)*64 + l
// ws element offset = (seg*131072 + t)*8  (seg: 0=Wg,1=Wv,2=Wo)  -> 6.29 MB total
// ---------------------------------------------------------------------------
__global__ __launch_bounds__(256) void prep_weights(
    const float* __restrict__ Wg, const float* __restrict__ Wv,
    const float* __restrict__ Wo, unsigned short* __restrict__ wsw) {
  int gtid = blockIdx.x * 256 + threadIdx.x;   // 0 .. 3*131072-1
  int seg = gtid >> 17;
  int t = gtid & 131071;
  int l = t & 63;
  unsigned short pk[8];
  if (seg < 2) {
    const float* W = (seg == 0) ? Wg : Wv;
    int ks = (t >> 6) & 7, nc = (t >> 9) & 1, c = (t >> 10) & 7, h = t >> 13;
    int col = c * 64 + nc * 32 + (l & 31);
    int rk = ks * 16 + ((l >> 5) << 3);
    const float* p = W + h * 65536 + rk * 512 + col;
#pragma unroll
    for (int j = 0; j < 8; ++j) pk[j] = f2bf(p[j * 512]);
  } else {
    int ks = (t >> 6) & 3, nt = (t >> 8) & 1, nc2 = (t >> 9) & 1, c = (t >> 10) & 7, h = t >> 13;
    int d = nc2 * 64 + nt * 32 + (l & 31);
    int f = c * 64 + ks * 16 + ((l >> 5) << 3);
    const float* p = Wo + h * 65536 + f * 128 + d;
#pragma unroll
    for (int j = 0; j < 8; ++j) pk[j] = f2bf(p[j * 128]);
  }
  us8 v;
#pragma unroll
  for (int j = 0; j < 8; ++j) v[j] = pk[j];
  *(us8*)(wsw + (long)gtid * 8) = v;
}

// ---------------------------------------------------------------------------
// Main fused kernel: one block = 64 rows of one head. 4 waves, wave quadrant
// (mr = w&1 -> rows mr*32, ncq = w>>1 -> GEMM1 cols ncq*32 / GEMM2 cols ncq*64)
// ---------------------------------------------------------------------------
__global__ __launch_bounds__(256, 2) void ffn_main(
    const float* __restrict__ z, const float* __restrict__ nw,
    const float* __restrict__ bgp, const float* __restrict__ bvp,
    const float* __restrict__ bop, const unsigned short* __restrict__ wsw,
    float* __restrict__ out) {
  __shared__ unsigned short xn_lds[BM * 128];  // swizzled: elem = row*128 + (k ^ ((row&15)<<3))
  __shared__ unsigned short h_lds[BM * 64];    // swizzled: elem = row*64  + (k ^ ((row&7)<<3))

  const int tid = threadIdx.x;
  const int l = tid & 63;
  const int w = tid >> 6;
  const int mr = w & 1;
  const int ncq = w >> 1;
  const int head = blockIdx.x >> 8;
  const int b0 = (blockIdx.x & 255) * BM;

  // ---- RMSNorm: coalesced float4 loads, 32-lane shfl row-reduce ----
#pragma unroll
  for (int i = 0; i < 8; ++i) {
    int f4 = tid + i * 256;            // 64 rows x 32 float4
    int row = f4 >> 5, c4 = f4 & 31;   // lanes 0-31 share a row
    const float4 zv = *(const float4*)(z + ((long)(b0 + row) * 16 + head) * 128 + c4 * 4);
    float ss = zv.x * zv.x + zv.y * zv.y + zv.z * zv.z + zv.w * zv.w;
    ss += __shfl_xor(ss, 1);
    ss += __shfl_xor(ss, 2);
    ss += __shfl_xor(ss, 4);
    ss += __shfl_xor(ss, 8);
    ss += __shfl_xor(ss, 16);
    float scale = rsqrtf(ss * (1.0f / 128.0f) + 1e-8f);
    const float4 wv4 = *(const float4*)(nw + c4 * 4);
    us4 xv;
    xv[0] = f2bf(zv.x * scale * wv4.x);
    xv[1] = f2bf(zv.y * scale * wv4.y);
    xv[2] = f2bf(zv.z * scale * wv4.z);
    xv[3] = f2bf(zv.w * scale * wv4.w);
    *(us4*)&xn_lds[row * 128 + ((c4 * 4) ^ ((row & 15) << 3))] = xv;
  }

  // ---- out accumulator init = z + bo (C-fragment layout; folds residual) ----
  f32x16 oacc[2];
#pragma unroll
  for (int nt = 0; nt < 2; ++nt) {
    int col = ncq * 64 + nt * 32 + (l & 31);
    float bov = bop[head * 128 + col];
#pragma unroll
    for (int r = 0; r < 16; ++r) {
      int rowo = mr * 32 + (r & 3) + ((r >> 2) << 3) + ((l >> 5) << 2);
      oacc[nt][r] = z[((long)(b0 + rowo) * 16 + head) * 128 + col] + bov;
    }
  }
  __syncthreads();

  // ---- hoist xn A-fragments into registers for the whole kernel ----
  const int arow = mr * 32 + (l & 31);
  const int kg = (l >> 5) << 3;
  bf16x8 a_xn[8];
#pragma unroll
  for (int ks = 0; ks < 8; ++ks)
    a_xn[ks] = *(const bf16x8*)&xn_lds[arow * 128 + ((ks * 16 + kg) ^ ((arow & 15) << 3))];

  const bf16x8* wsf = (const bf16x8*)wsw;

  for (int c = 0; c < 8; ++c) {
    // ---- GEMM1: g,v [32x32] per wave, K=128, B-frags straight from L2 ----
    const bf16x8* pg = wsf + ((long)((head * 8 + c) * 2 + ncq) * 8) * 64 + l;
    const bf16x8* pv = pg + 131072;
    bf16x8 bgf[8], bvf[8];
#pragma unroll
    for (int ks = 0; ks < 8; ++ks) bgf[ks] = pg[ks * 64];
#pragma unroll
    for (int ks = 0; ks < 8; ++ks) bvf[ks] = pv[ks * 64];
    f32x16 accg, accv;
#pragma unroll
    for (int r = 0; r < 16; ++r) { accg[r] = 0.f; accv[r] = 0.f; }
#pragma unroll
    for (int ks = 0; ks < 8; ++ks)
      accg = __builtin_amdgcn_mfma_f32_32x32x16_bf16(a_xn[ks], bgf[ks], accg, 0, 0, 0);
#pragma unroll
    for (int ks = 0; ks < 8; ++ks)
      accv = __builtin_amdgcn_mfma_f32_32x32x16_bf16(a_xn[ks], bvf[ks], accv, 0, 0, 0);

    // ---- bias + SiLU(g)*v -> bf16 -> swizzled LDS ----
    float bgs = bgp[head * 512 + c * 64 + ncq * 32 + (l & 31)];
    float bvs = bvp[head * 512 + c * 64 + ncq * 32 + (l & 31)];
#pragma unroll
    for (int r = 0; r < 16; ++r) {
      float gg = accg[r] + bgs;
      float vv = accv[r] + bvs;
      float hh = gg * vv / (1.0f + __expf(-gg));
      int rowh = mr * 32 + (r & 3) + ((r >> 2) << 3) + ((l >> 5) << 2);
      h_lds[rowh * 64 + ((ncq * 32 + (l & 31)) ^ ((rowh & 7) << 3))] = f2bf(hh);
    }
    __syncthreads();

    // ---- GEMM2: out[32x64] per wave += h[32x64-chunk] @ Wo-chunk ----
    bf16x8 a_h[4];
#pragma unroll
    for (int ks = 0; ks < 4; ++ks)
      a_h[ks] = *(const bf16x8*)&h_lds[arow * 64 + ((ks * 16 + kg) ^ ((arow & 7) << 3))];
    const bf16x8* po = wsf + 262144 + ((long)(((head * 8 + c) * 2 + ncq) * 2) * 4) * 64 + l;
    bf16x8 ofr[8];
#pragma unroll
    for (int q = 0; q < 8; ++q) ofr[q] = po[q * 64];
#pragma unroll
    for (int nt = 0; nt < 2; ++nt)
#pragma unroll
      for (int ks = 0; ks < 4; ++ks)
        oacc[nt] = __builtin_amdgcn_mfma_f32_32x32x16_bf16(a_h[ks], ofr[nt * 4 + ks], oacc[nt], 0, 0, 0);
    __syncthreads();  // h_lds consumed; safe to overwrite next chunk
  }

  // ---- epilogue: store fp32 (z + bo already folded in) ----
#pragma unroll
  for (int nt = 0; nt < 2; ++nt) {
    int col = ncq * 64 + nt * 32 + (l & 31);
#pragma unroll
    for (int r = 0; r < 16; ++r) {
      int rowo = mr * 32 + (r & 3) + ((r >> 2) << 3) + ((l >> 5) << 2);
      out[((long)(b0 + rowo) * 16 + head) * 128 + col] = oacc[nt][r];
    }
  }
}

extern "C" void kernel_launch(void* const* d_in, const int* in_sizes, int n_in,
                              void* d_out, int out_size, void* d_ws, size_t ws_size,
                              hipStream_t stream) {
  const float* z  = (const float*)d_in[0];
  const float* nw = (const float*)d_in[1];
  const float* Wg = (const float*)d_in[2];
  const float* bg = (const float*)d_in[3];
  const float* Wv = (const float*)d_in[4];
  const float* bv = (const float*)d_in[5];
  const float* Wo = (const float*)d_in[6];
  const float* bo = (const float*)d_in[7];
  float* out = (float*)d_out;
  unsigned short* wsw = (unsigned short*)d_ws;

  // 3 * 131072 fragment-threads, 8 bf16 each -> 6.29 MB in d_ws
  prep_weights<<<1536, 256, 0, stream>>>(Wg, Wv, Wo, wsw);
  // 16384/64 row-tiles * 16 heads; consecutive blocks share a head (L2 locality)
  ffn_main<<<4096, 256, 0, stream>>>(z, nw, bg, bv, bo, wsw, out);
}

// Round 2
// 412.970 us; speedup vs baseline: 1.2894x; 1.2894x over previous
//
#include <hip/hip_runtime.h>
#include <hip/hip_bf16.h>

typedef __attribute__((ext_vector_type(8))) short bf16x8;
typedef __attribute__((ext_vector_type(16))) float f32x16;
typedef __attribute__((ext_vector_type(4))) unsigned short us4;
typedef __attribute__((ext_vector_type(8))) unsigned short us8;

__device__ __forceinline__ unsigned short f2bf(float x) {
  unsigned u = __builtin_bit_cast(unsigned, x);
  u += 0x7fffu + ((u >> 16) & 1u);   // round-to-nearest-even
  return (unsigned short)(u >> 16);
}

__device__ __forceinline__ void gld_lds16(const void* g, void* l) {
  __builtin_amdgcn_global_load_lds(
      (const __attribute__((address_space(1))) unsigned int*)g,
      (__attribute__((address_space(3))) unsigned int*)l, 16, 0, 0);
}

// ---------------------------------------------------------------------------
// Pre-pass: fp32 -> bf16 in MFMA B-fragment order. LDS-transposed so BOTH
// global reads and global writes are coalesced.
// g/v frag (seg 0/1), per (h,c): t' = (nc*8+ks)*64+l, value j =
//   W[h][k=ks*16+(l>>5)*8+j][n=c*64+nc*32+(l&31)]
// o frag (seg 2), per (h,c): t' = ((nc2*2+nt)*4+ks)*64+l, value j =
//   Wo[h][f=c*64+ks*16+(l>>5)*8+j][d=nc2*64+nt*32+(l&31)]
// ws element (us) offset = seg*1048576 + (h*8+c)*8192 + t'*8
// ---------------------------------------------------------------------------
__global__ __launch_bounds__(256) void prep_weights(
    const float* __restrict__ Wg, const float* __restrict__ Wv,
    const float* __restrict__ Wo, unsigned short* __restrict__ wsw) {
  __shared__ unsigned short T[16384];
  const int b = blockIdx.x;
  const int tid = threadIdx.x;
  if (b < 256) {
    int seg = b >> 7, h = (b >> 3) & 15, c = b & 7;
    const float* W = (seg == 0 ? Wg : Wv) + h * 65536 + c * 64;
#pragma unroll
    for (int q = 0; q < 8; ++q) {
      int idx = tid + q * 256;          // 2048 float4: 128 k-rows x 16 f4
      int k = idx >> 4, c4 = (idx & 15) << 2;
      const float4 v4 = *(const float4*)(W + k * 512 + c4);
      T[(c4 + 0) * 128 + (k ^ (((c4 + 0) & 7) << 4))] = f2bf(v4.x);
      T[(c4 + 1) * 128 + (k ^ (((c4 + 1) & 7) << 4))] = f2bf(v4.y);
      T[(c4 + 2) * 128 + (k ^ (((c4 + 2) & 7) << 4))] = f2bf(v4.z);
      T[(c4 + 3) * 128 + (k ^ (((c4 + 3) & 7) << 4))] = f2bf(v4.w);
    }
    __syncthreads();
#pragma unroll
    for (int q = 0; q < 4; ++q) {
      int f = tid + q * 256;            // 1024 frags
      int l = f & 63, ks = (f >> 6) & 7, nc = f >> 9;
      int n = nc * 32 + (l & 31);
      int k0 = ks * 16 + ((l >> 5) << 3);
      us8 v = *(const us8*)&T[n * 128 + (k0 ^ ((n & 7) << 4))];
      *(us8*)(wsw + (long)seg * 1048576 + (long)(h * 8 + c) * 8192 + f * 8) = v;
    }
  } else {
    int bb = b - 256, h = bb >> 3, c = bb & 7;
    const float* W = Wo + h * 65536 + c * 64 * 128;
#pragma unroll
    for (int q = 0; q < 8; ++q) {
      int idx = tid + q * 256;          // 2048 float4: 64 f-rows x 32 f4
      int fr = idx >> 5, d4 = (idx & 31) << 2;
      const float4 v4 = *(const float4*)(W + fr * 128 + d4);
      T[(d4 + 0) * 64 + (fr ^ (((d4 + 0) & 7) << 3))] = f2bf(v4.x);
      T[(d4 + 1) * 64 + (fr ^ (((d4 + 1) & 7) << 3))] = f2bf(v4.y);
      T[(d4 + 2) * 64 + (fr ^ (((d4 + 2) & 7) << 3))] = f2bf(v4.z);
      T[(d4 + 3) * 64 + (fr ^ (((d4 + 3) & 7) << 3))] = f2bf(v4.w);
    }
    __syncthreads();
#pragma unroll
    for (int q = 0; q < 4; ++q) {
      int f = tid + q * 256;
      int l = f & 63, ks = (f >> 6) & 3, nt = (f >> 8) & 1, nc2 = f >> 9;
      int d = nc2 * 64 + nt * 32 + (l & 31);
      int f0 = ks * 16 + ((l >> 5) << 3);
      us8 v = *(const us8*)&T[d * 64 + (f0 ^ ((d & 7) << 3))];
      *(us8*)(wsw + 2097152l + (long)(h * 8 + c) * 8192 + f * 8) = v;
    }
  }
}

// ---------------------------------------------------------------------------
// Main fused kernel: block = 128 rows x 1 head, 512 threads (8 waves).
// Wave (mr = w&3 -> rows mr*32, ncq = w>>2 -> GEMM1 cols ncq*32 / GEMM2 cols
// ncq*64). Weights double-buffered in LDS via global_load_lds; mid-barrier
// keeps staging in flight; one vmcnt-drain per chunk (hidden).
// ---------------------------------------------------------------------------
__device__ __forceinline__ void stage_chunk(const unsigned short* __restrict__ wsw,
                                            unsigned short* wb, int hc, int tid) {
  const unsigned short* src0 = wsw + (long)hc * 8192;
#pragma unroll
  for (int j = 0; j < 6; ++j) {
    int u = tid + j * 512;              // 3072 x 16B = 48KB (g|v|o)
    int seg = u >> 10, off = u & 1023;
    gld_lds16(src0 + (long)seg * 1048576 + off * 8, wb + u * 8);
  }
}

__global__ __launch_bounds__(512, 2) void ffn_main(
    const float* __restrict__ z, const float* __restrict__ nw,
    const float* __restrict__ bgp, const float* __restrict__ bvp,
    const float* __restrict__ bop, const unsigned short* __restrict__ wsw,
    float* __restrict__ out) {
  __shared__ unsigned short xn_lds[128 * 128];   // 32KB, swz: k ^ ((row&15)<<3)
  __shared__ unsigned short h_lds[128 * 64];     // 16KB, swz: k ^ ((row&7)<<3)
  __shared__ unsigned short wbuf[2][24576];      // 2 x 48KB

  const int tid = threadIdx.x;
  const int l = tid & 63;
  const int w = tid >> 6;
  const int mr = w & 3;
  const int ncq = w >> 2;
  // XCD-aware mapping: same-XCD blocks work on the same head
  const int x = blockIdx.x & 7, i = blockIdx.x >> 3;
  const int head = i >> 4;
  const int b0 = ((((i & 15) << 3) + x) << 7);
  const int hc0 = head * 8;

  stage_chunk(wsw, wbuf[0], hc0, tid);

  // ---- RMSNorm: float4 loads, 32-lane shfl row-reduce ----
#pragma unroll
  for (int it = 0; it < 8; ++it) {
    int f4 = tid + it * 512;             // 128 rows x 32 f4
    int row = f4 >> 5, c4 = (f4 & 31) << 2;
    const float4 zv = *(const float4*)(z + ((long)(b0 + row) * 16 + head) * 128 + c4);
    float ss = zv.x * zv.x + zv.y * zv.y + zv.z * zv.z + zv.w * zv.w;
    ss += __shfl_xor(ss, 1);
    ss += __shfl_xor(ss, 2);
    ss += __shfl_xor(ss, 4);
    ss += __shfl_xor(ss, 8);
    ss += __shfl_xor(ss, 16);
    float scale = rsqrtf(ss * (1.0f / 128.0f) + 1e-8f);
    const float4 wv4 = *(const float4*)(nw + c4);
    us4 xv;
    xv[0] = f2bf(zv.x * scale * wv4.x);
    xv[1] = f2bf(zv.y * scale * wv4.y);
    xv[2] = f2bf(zv.z * scale * wv4.z);
    xv[3] = f2bf(zv.w * scale * wv4.w);
    *(us4*)&xn_lds[row * 128 + (c4 ^ ((row & 15) << 3))] = xv;
  }

  // ---- out accumulator init = z + bo (folds residual) ----
  f32x16 oacc[2];
#pragma unroll
  for (int nt = 0; nt < 2; ++nt) {
    int col = ncq * 64 + nt * 32 + (l & 31);
    float bov = bop[head * 128 + col];
#pragma unroll
    for (int r = 0; r < 16; ++r) {
      int rowo = mr * 32 + (r & 3) + ((r >> 2) << 3) + ((l >> 5) << 2);
      oacc[nt][r] = z[((long)(b0 + rowo) * 16 + head) * 128 + col] + bov;
    }
  }
  __syncthreads();   // xn ready; chunk-0 stage drained

  const int arow = mr * 32 + (l & 31);
  const int kg = (l >> 5) << 3;
  bf16x8 a_xn[8];
#pragma unroll
  for (int ks = 0; ks < 8; ++ks)
    a_xn[ks] = *(const bf16x8*)&xn_lds[arow * 128 + ((ks * 16 + kg) ^ ((arow & 15) << 3))];

  int cur = 0;
  for (int c = 0; c < 8; ++c) {
    stage_chunk(wsw, wbuf[cur ^ 1], hc0 + ((c + 1) & 7), tid);  // in flight across mid-barrier
    float bgs = bgp[head * 512 + c * 64 + ncq * 32 + (l & 31)];
    float bvs = bvp[head * 512 + c * 64 + ncq * 32 + (l & 31)];
    const unsigned short* wb = wbuf[cur];

    // ---- GEMM1: g,v [32x32] per wave, K=128, B-frags from LDS ----
    bf16x8 bgf[8], bvf[8];
#pragma unroll
    for (int ks = 0; ks < 8; ++ks)
      bgf[ks] = *(const bf16x8*)&wb[(ncq * 8 + ks) * 512 + l * 8];
    f32x16 accg, accv;
#pragma unroll
    for (int r = 0; r < 16; ++r) { accg[r] = 0.f; accv[r] = 0.f; }
#pragma unroll
    for (int ks = 0; ks < 8; ++ks)
      accg = __builtin_amdgcn_mfma_f32_32x32x16_bf16(a_xn[ks], bgf[ks], accg, 0, 0, 0);
#pragma unroll
    for (int ks = 0; ks < 8; ++ks)
      bvf[ks] = *(const bf16x8*)&wb[8192 + (ncq * 8 + ks) * 512 + l * 8];
#pragma unroll
    for (int ks = 0; ks < 8; ++ks)
      accv = __builtin_amdgcn_mfma_f32_32x32x16_bf16(a_xn[ks], bvf[ks], accv, 0, 0, 0);

    // ---- bias + SiLU(g)*v -> bf16 -> swizzled LDS ----
#pragma unroll
    for (int r = 0; r < 16; ++r) {
      float gg = accg[r] + bgs;
      float vv = accv[r] + bvs;
      float e = __expf(-gg);
      float den = 1.0f + e, rc;
      asm("v_rcp_f32 %0, %1" : "=v"(rc) : "v"(den));
      float hh = gg * vv * rc;
      int rowh = mr * 32 + (r & 3) + ((r >> 2) << 3) + ((l >> 5) << 2);
      h_lds[rowh * 64 + ((ncq * 32 + (l & 31)) ^ ((rowh & 7) << 3))] = f2bf(hh);
    }
    // mid-barrier: LDS drained, staging loads stay in flight (no vmcnt)
    asm volatile("s_waitcnt lgkmcnt(0)" ::: "memory");
    __builtin_amdgcn_s_barrier();
    __builtin_amdgcn_sched_barrier(0);

    // ---- GEMM2: out[32x64] per wave += h-chunk @ Wo-chunk ----
    bf16x8 a_h[4];
#pragma unroll
    for (int ks = 0; ks < 4; ++ks)
      a_h[ks] = *(const bf16x8*)&h_lds[arow * 64 + ((ks * 16 + kg) ^ ((arow & 7) << 3))];
    const unsigned short* wo = wb + 16384;
#pragma unroll
    for (int nt = 0; nt < 2; ++nt)
#pragma unroll
      for (int ks = 0; ks < 4; ++ks) {
        bf16x8 bo8 = *(const bf16x8*)&wo[(((ncq * 2 + nt) * 4 + ks) * 64 + l) * 8];
        oacc[nt] = __builtin_amdgcn_mfma_f32_32x32x16_bf16(a_h[ks], bo8, oacc[nt], 0, 0, 0);
      }
    __syncthreads();   // drains staging vmcnt (hidden) + protects h_lds/wbuf reuse
    cur ^= 1;
  }

  // ---- epilogue: store fp32 (z + bo already folded) ----
#pragma unroll
  for (int nt = 0; nt < 2; ++nt) {
    int col = ncq * 64 + nt * 32 + (l & 31);
#pragma unroll
    for (int r = 0; r < 16; ++r) {
      int rowo = mr * 32 + (r & 3) + ((r >> 2) << 3) + ((l >> 5) << 2);
      out[((long)(b0 + rowo) * 16 + head) * 128 + col] = oacc[nt][r];
    }
  }
}

extern "C" void kernel_launch(void* const* d_in, const int* in_sizes, int n_in,
                              void* d_out, int out_size, void* d_ws, size_t ws_size,
                              hipStream_t stream) {
  const float* z  = (const float*)d_in[0];
  const float* nw = (const float*)d_in[1];
  const float* Wg = (const float*)d_in[2];
  const float* bg = (const float*)d_in[3];
  const float* Wv = (const float*)d_in[4];
  const float* bv = (const float*)d_in[5];
  const float* Wo = (const float*)d_in[6];
  const float* bo = (const float*)d_in[7];
  float* out = (float*)d_out;
  unsigned short* wsw = (unsigned short*)d_ws;

  prep_weights<<<384, 256, 0, stream>>>(Wg, Wv, Wo, wsw);
  ffn_main<<<2048, 512, 0, stream>>>(z, nw, bg, bv, bo, wsw, out);
}